// Round 1
// baseline (1110.100 us; speedup 1.0000x reference)
//
#include <hip/hip_runtime.h>
#include <hip/hip_bf16.h>

#define B_   128
#define S_   2048
#define DM   512
#define H_   8
#define E_   4096   // H_*DM
#define NCH  8      // S-chunks per batch
#define CS   256    // chunk size (S_/NCH)

// ---------------- Kernel 1: q projection (+bias, pre-scaled by 1/sqrt(512)) ----
// grid (16 e-tiles, 16 b-tiles), block 256. qs[b][e], e = h*512+d.
__global__ __launch_bounds__(256) void qproj_kernel(
    const float* __restrict__ query, const float* __restrict__ W_in,
    const float* __restrict__ b_in, float* __restrict__ qs) {
  __shared__ float qt[8][DM];
  const int tid = threadIdx.x;
  const int b0 = blockIdx.y * 8;
  for (int i = 0; i < 16; ++i) {
    int idx = tid + i * 256;          // 0..4095
    int bb = idx >> 9, k = idx & 511;
    qt[bb][k] = query[(size_t)(b0 + bb) * DM + k];
  }
  __syncthreads();
  const int e = blockIdx.x * 256 + tid;
  const float4* wrow = (const float4*)(W_in + (size_t)e * DM);
  float bias = b_in[e];
  float acc[8];
#pragma unroll
  for (int j = 0; j < 8; ++j) acc[j] = bias;
  for (int kk = 0; kk < DM / 4; ++kk) {
    float4 w = wrow[kk];
#pragma unroll
    for (int j = 0; j < 8; ++j) {
      float4 qv = ((const float4*)qt[j])[kk];   // wave-broadcast
      acc[j] += w.x * qv.x + w.y * qv.y + w.z * qv.z + w.w * qv.w;
    }
  }
  const float scale = 0.04419417382415922f;  // 1/sqrt(512)
#pragma unroll
  for (int j = 0; j < 8; ++j)
    qs[(size_t)(b0 + j) * E_ + e] = acc[j] * scale;
}

// ---------------- Kernel 2: fused masked attention, per-chunk partials --------
// grid (NCH, B_), block 256. Writes unnormalized O, plus m,l per (b,chunk,h).
__global__ __launch_bounds__(256) void attn_kernel(
    const float* __restrict__ key, const float* __restrict__ value,
    const int* __restrict__ mask, const float* __restrict__ qs,
    float* __restrict__ Opart, float* __restrict__ mpart,
    float* __restrict__ lpart) {
  __shared__ float qlds[E_];          // 16 KB
  __shared__ float sc[H_][CS];        // 8 KB  (scores -> p, compacted)
  __shared__ int   sidx[CS];          // compacted unmasked s offsets
  __shared__ int   scnt;
  const int tid = threadIdx.x;
  const int b  = blockIdx.y;
  const int cx = blockIdx.x;
  const int s0 = cx * CS;

  // stage q for all 8 heads
  {
    const float4* src = (const float4*)(qs + (size_t)b * E_);
    float4* dst = (float4*)qlds;
    for (int i = 0; i < 4; ++i) dst[tid + i * 256] = src[tid + i * 256];
  }
  if (tid == 0) scnt = 0;
  __syncthreads();

  // compact unmasked indices (order irrelevant: softmax is a sum)
  int mk = mask[(size_t)b * S_ + s0 + tid];
  if (mk != 0) { int p = atomicAdd(&scnt, 1); sidx[p] = tid; }
  __syncthreads();
  const int cnt = scnt;

  // Phase A: scores for unmasked rows only (skips ~half of key traffic)
  if (tid < cnt) {
    const int s = s0 + sidx[tid];
    const float4* krow = (const float4*)(key + ((size_t)b * S_ + s) * DM);
    const float4* q4 = (const float4*)qlds;
    float acc[8] = {0, 0, 0, 0, 0, 0, 0, 0};
    for (int kk = 0; kk < DM / 4; ++kk) {
      float4 kv = krow[kk];
#pragma unroll
      for (int h = 0; h < 8; ++h) {
        float4 qv = q4[h * (DM / 4) + kk];   // wave-broadcast
        acc[h] += kv.x * qv.x + kv.y * qv.y + kv.z * qv.z + kv.w * qv.w;
      }
    }
#pragma unroll
    for (int h = 0; h < 8; ++h) sc[h][tid] = acc[h];
  }
  __syncthreads();

  // Phase A2: per-head max & sum over compacted scores; store p in-place.
  {
    const int g = tid >> 5, l32 = tid & 31;   // head g, half-wave lane
    float m = -3.0e38f;
    float v[8];
#pragma unroll
    for (int j = 0; j < 8; ++j) {
      int idx = l32 + 32 * j;
      v[j] = (idx < cnt) ? sc[g][idx] : -3.0e38f;
      m = fmaxf(m, v[j]);
    }
#pragma unroll
    for (int off = 16; off; off >>= 1) m = fmaxf(m, __shfl_xor(m, off, 64));
    float lsum = 0.f;
#pragma unroll
    for (int j = 0; j < 8; ++j) {
      int idx = l32 + 32 * j;
      if (idx < cnt) {
        float p = __expf(v[j] - m);
        lsum += p;
        sc[g][idx] = p;
      }
    }
#pragma unroll
    for (int off = 16; off; off >>= 1) lsum += __shfl_xor(lsum, off, 64);
    if (l32 == 0) {
      mpart[((size_t)b * NCH + cx) * H_ + g] = m;
      lpart[((size_t)b * NCH + cx) * H_ + g] = lsum;
    }
  }
  __syncthreads();

  // Phase B: O[h][d] += p * v  over unmasked rows, 4h x 4d register tile
  const int dg = tid & 127, hg = tid >> 7;       // d0 = dg*4, heads hg*4..+3
  float accO[4][4] = {};
  const float4* vbase = (const float4*)(value + ((size_t)b * S_ + s0) * DM);
  for (int ss = 0; ss < cnt; ++ss) {
    const int srow = sidx[ss];                    // LDS broadcast
    float4 vv = vbase[(size_t)srow * (DM / 4) + dg];  // coalesced
#pragma unroll
    for (int i = 0; i < 4; ++i) {
      float p = sc[hg * 4 + i][ss];               // wave-broadcast
      accO[i][0] += p * vv.x;
      accO[i][1] += p * vv.y;
      accO[i][2] += p * vv.z;
      accO[i][3] += p * vv.w;
    }
  }
#pragma unroll
  for (int i = 0; i < 4; ++i) {
    size_t off = ((((size_t)b * NCH + cx) * H_) + hg * 4 + i) * DM + dg * 4;
    float4 o; o.x = accO[i][0]; o.y = accO[i][1]; o.z = accO[i][2]; o.w = accO[i][3];
    *(float4*)(Opart + off) = o;
  }
}

// ---------------- Kernel 3: combine chunk partials -> x[b][e] ---------------
__global__ __launch_bounds__(256) void combine_kernel(
    const float* __restrict__ Opart, const float* __restrict__ mpart,
    const float* __restrict__ lpart, float* __restrict__ xbuf) {
  const int idx = blockIdx.x * 256 + threadIdx.x;   // 0..524287
  const int b = idx >> 12, e = idx & (E_ - 1);
  const int h = e >> 9, d = e & 511;
  float mc[NCH], lc[NCH];
  float M = -3.0e38f;
#pragma unroll
  for (int c = 0; c < NCH; ++c) {
    mc[c] = mpart[((size_t)b * NCH + c) * H_ + h];
    lc[c] = lpart[((size_t)b * NCH + c) * H_ + h];
    M = fmaxf(M, mc[c]);
  }
  float L = 0.f, acc = 0.f;
#pragma unroll
  for (int c = 0; c < NCH; ++c) {
    float w = __expf(mc[c] - M);
    L += w * lc[c];
    acc += w * Opart[(((size_t)b * NCH + c) * H_ + h) * DM + d];
  }
  xbuf[idx] = acc / L;
}

// ---------------- Kernel 4: out = x @ W_out^T + b_out -----------------------
// M=128,N=4096,K=4096. Block tile 64b x 32f, Kc=32, grid (128,2), 256 thr.
__global__ __launch_bounds__(256) void outproj_kernel(
    const float* __restrict__ xbuf, const float* __restrict__ W_out,
    const float* __restrict__ b_out, float* __restrict__ out) {
  __shared__ float xs[32][68];   // [k][b], padded
  __shared__ float wsz[32][36];  // [k][f], padded
  const int tid = threadIdx.x;
  const int f0 = blockIdx.x * 32;
  const int b0 = blockIdx.y * 64;
  const int bg = tid & 15;        // 16 groups * 4 b = 64
  const int fg = tid >> 4;        // 16 groups * 2 f = 32
  const int row = tid >> 3;       // 0..31
  const int col = tid & 7;        // 0..7  (k-chunk of 4)
  float accC[4][2] = {};
  float4 xa, xb, wv;

  auto load_tile = [&](int k0) {
    xa = *(const float4*)&xbuf[(size_t)(b0 + row) * E_ + k0 + col * 4];
    xb = *(const float4*)&xbuf[(size_t)(b0 + 32 + row) * E_ + k0 + col * 4];
    wv = *(const float4*)&W_out[(size_t)(f0 + row) * E_ + k0 + col * 4];
  };
  load_tile(0);
  for (int t = 0; t < E_ / 32; ++t) {
    __syncthreads();
    xs[col * 4 + 0][row] = xa.x; xs[col * 4 + 1][row] = xa.y;
    xs[col * 4 + 2][row] = xa.z; xs[col * 4 + 3][row] = xa.w;
    xs[col * 4 + 0][32 + row] = xb.x; xs[col * 4 + 1][32 + row] = xb.y;
    xs[col * 4 + 2][32 + row] = xb.z; xs[col * 4 + 3][32 + row] = xb.w;
    wsz[col * 4 + 0][row] = wv.x; wsz[col * 4 + 1][row] = wv.y;
    wsz[col * 4 + 2][row] = wv.z; wsz[col * 4 + 3][row] = wv.w;
    __syncthreads();
    if (t + 1 < E_ / 32) load_tile((t + 1) * 32);   // overlap with compute
#pragma unroll
    for (int k = 0; k < 32; ++k) {
      float4 av = *(const float4*)&xs[k][bg * 4];
      float2 wv2 = *(const float2*)&wsz[k][fg * 2];
      accC[0][0] += av.x * wv2.x; accC[0][1] += av.x * wv2.y;
      accC[1][0] += av.y * wv2.x; accC[1][1] += av.y * wv2.y;
      accC[2][0] += av.z * wv2.x; accC[2][1] += av.z * wv2.y;
      accC[3][0] += av.w * wv2.x; accC[3][1] += av.w * wv2.y;
    }
  }
  const int fo = f0 + fg * 2;
#pragma unroll
  for (int i = 0; i < 4; ++i) {
#pragma unroll
    for (int j = 0; j < 2; ++j)
      out[(size_t)(b0 + bg * 4 + i) * E_ + fo + j] = accC[i][j] + b_out[fo + j];
  }
}

extern "C" void kernel_launch(void* const* d_in, const int* in_sizes, int n_in,
                              void* d_out, int out_size, void* d_ws, size_t ws_size,
                              hipStream_t stream) {
  const float* query = (const float*)d_in[0];
  const float* key   = (const float*)d_in[1];
  const float* value = (const float*)d_in[2];
  const int*   mask  = (const int*)d_in[3];
  const float* W_in  = (const float*)d_in[4];
  const float* b_in  = (const float*)d_in[5];
  const float* W_out = (const float*)d_in[6];
  const float* b_out = (const float*)d_in[7];
  float* out = (float*)d_out;

  float* ws    = (float*)d_ws;
  float* qs    = ws;                       // 128*4096            = 524288
  float* Opart = qs + 524288;              // 128*8*8*512         = 4194304
  float* mpart = Opart + 4194304;          // 128*8*8             = 8192
  float* lpart = mpart + 8192;             // 8192
  float* xbuf  = lpart + 8192;             // 524288

  qproj_kernel<<<dim3(16, 16), 256, 0, stream>>>(query, W_in, b_in, qs);
  attn_kernel<<<dim3(NCH, B_), 256, 0, stream>>>(key, value, mask, qs,
                                                 Opart, mpart, lpart);
  combine_kernel<<<2048, 256, 0, stream>>>(Opart, mpart, lpart, xbuf);
  outproj_kernel<<<dim3(128, 2), 256, 0, stream>>>(xbuf, W_out, b_out, out);
}